// Round 9
// baseline (1286.655 us; speedup 1.0000x reference)
//
#include <hip/hip_runtime.h>
#include <hip/hip_fp16.h>
#include <math.h>

#define NN 50000
#define EE 800000
#define GG 64
#define NT  (NN / 16)            // 3125 16-node tiles (exact)
#define MMB 1024                 // persistent GEMM blocks in merged part+mm kernel

#define EPB 4096                 // edges per partition block
#define NPB ((EE + EPB - 1) / EPB)   // 196 partition blocks
#define NB  ((NN + 255) >> 8)        // 196 dst buckets (256 nodes each)
#define CAP 4608                 // bucket edge capacity: mean 4082 + 8.2 sigma
#define CAPP 6912                // + self slots + 8-align padding (mult of 8)
#define NTA ((NN + 63) / 64)         // 782 agg tiles of 64 dsts
#define TPB 4                    // tiles per spmm block
#define NSB (((NTA + TPB - 1) / TPB) * 8)  // spmm grid

typedef _Float16 f16x8 __attribute__((ext_vector_type(8)));
typedef float f32x4 __attribute__((ext_vector_type(4)));
typedef unsigned short u16;
typedef u16 u16x8 __attribute__((ext_vector_type(8)));

__device__ __forceinline__ float lrelu(float x) { return x > 0.f ? x : 0.2f * x; }

// ---------------- fp16 weight prep (tiny, runs before merged part+mm) ----------
__global__ void k_prep(const float* __restrict__ W1, const float* __restrict__ W2,
                       const float* __restrict__ W3, const float* __restrict__ aw1,
                       const float* __restrict__ rw1, const float* __restrict__ cw1,
                       _Float16* __restrict__ wt1, _Float16* __restrict__ wt2,
                       _Float16* __restrict__ wt3, _Float16* __restrict__ wcat) {
  const int t = blockIdx.x * 256 + threadIdx.x;
  if (t < 32768) {
    const int c = t >> 7, k = t & 127;
    wt1[t] = (_Float16)W1[k * 256 + c];
  } else if (t < 49152) {
    const int u = t - 32768, c = u >> 6, k = u & 63;
    wt2[u] = (_Float16)W2[k * 256 + c];
  } else if (t < 65536) {
    const int u = t - 49152, c = u >> 6, k = u & 63;
    wt3[u] = (_Float16)W3[k * 256 + c];
  } else if (t < 71680) {
    const int u = t - 65536, c = u >> 6, k = u & 63;
    float v = (c < 32) ? aw1[k * 32 + c] : (c < 64) ? rw1[k * 32 + (c - 32)]
                                                    : cw1[k * 32 + (c - 64)];
    wcat[u] = (_Float16)v;
  }
}

// stage wave's fp32 frags -> per-wave LDS fp16 tile (stride 68: conflict-free)
// -> 16B sliced global stores. hS layout: [cg][node][hh*8+j], 64 B/node/slice.
__device__ __forceinline__ void store_sliced(_Float16* __restrict__ hS,
                                             _Float16* __restrict__ lds,  // [16*68]
                                             const f32x4* accv, int row0, int wv,
                                             int quad, int nn, int lane) {
#pragma unroll
  for (int ct = 0; ct < 4; ++ct)
#pragma unroll
    for (int r = 0; r < 4; ++r)
      lds[(quad * 4 + r) * 68 + ct * 16 + nn] = (_Float16)accv[ct][r];
#pragma unroll
  for (int it = 0; it < 2; ++it) {
    const int idx = it * 64 + lane;
    const int row = idx >> 3, cgx = idx & 7;
    const f16x8 v = *(const f16x8*)&lds[row * 68 + cgx * 8];
    *(f16x8*)&hS[((size_t)cgx * NN + row0 + row) * 32 + wv * 8] = v;
  }
}

// ------- pass 1: edge partition into 196 dst-buckets (block-private chunks)
//         merged with layer-1 MFMA GEMM (writes channel-sliced h + als/ald) -------
__global__ __launch_bounds__(256) void k_part(const int* __restrict__ ei,
                                              int* __restrict__ gcur,
                                              unsigned* __restrict__ ebuf,
                                              const float* __restrict__ xin,
                                              const _Float16* __restrict__ wt,
                                              const float* __restrict__ a_s,
                                              const float* __restrict__ a_d,
                                              _Float16* __restrict__ hS,
                                              float* __restrict__ als,
                                              float* __restrict__ ald) {
  if (blockIdx.x < NPB) {
    __shared__ int hist[NB], base[NB], lcur[NB];
    const int tid = threadIdx.x;
    const int e0 = blockIdx.x * EPB;
    const int e1 = min(e0 + EPB, EE);
    for (int i = tid; i < NB; i += 256) hist[i] = 0;
    __syncthreads();
    for (int e = e0 + tid; e < e1; e += 256)
      atomicAdd(&hist[ei[EE + e] >> 8], 1);
    __syncthreads();
    for (int i = tid; i < NB; i += 256) {
      base[i] = (hist[i] > 0) ? atomicAdd(&gcur[i], hist[i]) : 0;
      lcur[i] = 0;
    }
    __syncthreads();
    for (int e = e0 + tid; e < e1; e += 256) {
      const int src = ei[e], dst = ei[EE + e];
      const int b = dst >> 8;
      const int sl = base[b] + atomicAdd(&lcur[b], 1);
      if (sl < CAP)
        ebuf[(size_t)b * CAP + sl] = ((unsigned)(dst & 255) << 16) | (unsigned)src;
    }
    return;
  }
  // ---- layer-1 GEMM: h = x@W1 (fp32 x, in-register cvt), fused al_s/al_d ----
  __shared__ _Float16 stg[4][16 * 68];
  constexpr int K = 128, KC = K / 32;
  const int lane = threadIdx.x & 63;
  const int wv = threadIdx.x >> 6;
  const int quad = lane >> 4, nn = lane & 15;
  f16x8 bf[KC][4];
  float asf[4], adf[4];
#pragma unroll
  for (int ct = 0; ct < 4; ++ct) {
    const int col = wv * 64 + ct * 16 + nn;
#pragma unroll
    for (int kc = 0; kc < KC; ++kc)
      bf[kc][ct] = *(const f16x8*)&wt[(size_t)col * K + kc * 32 + quad * 8];
    asf[ct] = a_s[col];
    adf[ct] = a_d[col];
  }
  for (int rt = blockIdx.x - NPB; rt < NT; rt += MMB) {
    const int row0 = rt * 16;
    const float* xrow = xin + (size_t)(row0 + nn) * K + quad * 8;
    f16x8 af[KC];
#pragma unroll
    for (int kc = 0; kc < KC; ++kc) {
      const float4 u0 = *(const float4*)(xrow + kc * 32);
      const float4 u1 = *(const float4*)(xrow + kc * 32 + 4);
      af[kc][0] = (_Float16)u0.x; af[kc][1] = (_Float16)u0.y;
      af[kc][2] = (_Float16)u0.z; af[kc][3] = (_Float16)u0.w;
      af[kc][4] = (_Float16)u1.x; af[kc][5] = (_Float16)u1.y;
      af[kc][6] = (_Float16)u1.z; af[kc][7] = (_Float16)u1.w;
    }
    f32x4 accv[4];
#pragma unroll
    for (int ct = 0; ct < 4; ++ct) {
      f32x4 acc = {0.f, 0.f, 0.f, 0.f};
#pragma unroll
      for (int kc = 0; kc < KC; ++kc)
        acc = __builtin_amdgcn_mfma_f32_16x16x32_f16(af[kc], bf[kc][ct], acc, 0, 0, 0);
      accv[ct] = acc;
    }
    store_sliced(hS, stg[wv], accv, row0, wv, quad, nn, lane);
    float sa[4] = {0.f, 0.f, 0.f, 0.f}, sd[4] = {0.f, 0.f, 0.f, 0.f};
#pragma unroll
    for (int ct = 0; ct < 4; ++ct)
#pragma unroll
      for (int r = 0; r < 4; ++r) {
        sa[r] = fmaf(accv[ct][r], asf[ct], sa[r]);
        sd[r] = fmaf(accv[ct][r], adf[ct], sd[r]);
      }
#pragma unroll
    for (int off = 1; off <= 8; off <<= 1)
#pragma unroll
      for (int r = 0; r < 4; ++r) {
        sa[r] += __shfl_xor(sa[r], off, 64);
        sd[r] += __shfl_xor(sd[r], off, 64);
      }
    if (nn == 0) {
#pragma unroll
      for (int r = 0; r < 4; ++r) {
        als[(size_t)(row0 + quad * 4 + r) * 4 + wv] = sa[r];
        ald[(size_t)(row0 + quad * 4 + r) * 4 + wv] = sd[r];
      }
    }
  }
}

// ------- pass 2: per-bucket compact CSR (u16 src ids), SELF at slot 0,
//         rows padded to multiples of 8 (16B) — pad slots = own node id -------
__global__ __launch_bounds__(256) void k_csr(const int* __restrict__ gcur,
                                             const unsigned* __restrict__ ebuf,
                                             int* __restrict__ cnt,
                                             int* __restrict__ roff,
                                             u16* __restrict__ csr) {
  __shared__ int c256[256], pre[256], cur[256], wsum[4];
  const int b = blockIdx.x, tid = threadIdx.x;
  c256[tid] = 0;
  __syncthreads();
  const int nE = min(gcur[b], CAP);
  const unsigned* eb = ebuf + (size_t)b * CAP;
  for (int i = tid; i < nE; i += 256) atomicAdd(&c256[eb[i] >> 16], 1);
  __syncthreads();
  const int v = c256[tid] + 1;        // true deg incl self
  const int v8 = (v + 7) & ~7;        // padded row length (16B multiple)
  {
    const int lane = tid & 63, wid = tid >> 6;
    int x = v8;
#pragma unroll
    for (int off = 1; off < 64; off <<= 1) {
      const int y = __shfl_up(x, off, 64);
      if (lane >= off) x += y;
    }
    if (lane == 63) wsum[wid] = x;
    __syncthreads();
    int wo = 0;
    for (int w = 0; w < wid; ++w) wo += wsum[w];
    pre[tid] = wo + x - v8;
    cur[tid] = 1;  // slot 0 = self
  }
  __syncthreads();
  const int node = (b << 8) + tid;
  const int ro = b * CAPP + pre[tid];
  if (node < NN) {
    cnt[node] = v;
    roff[node] = ro;
    csr[ro] = (u16)node;  // self-loop
    for (int i = v; i < v8; ++i) csr[ro + i] = (u16)node;  // padding (p masked)
  }
  for (int i = tid; i < nE; i += 256) {
    const unsigned p = eb[i];
    const int dl = (int)(p >> 16), src = (int)(p & 0xFFFFu);
    const int slot = atomicAdd(&cur[dl], 1);
    csr[b * CAPP + pre[dl] + slot] = (u16)src;
  }
}

// ------- channel-sliced SpMM with fused unnormalized softmax -------
// slice cg = blockIdx%8 -> XCD round-robin (per-XCD hS slice 3.2MB + als 0.8MB
// L2-resident; csr stream now u16 = 1.7MB/XCD). One 16B load = 8 edge ids;
// 8 als + 8 hv gathers in flight. ONE lane per (dst, head); den lane-local.
// 4 tiles per block (longer-lived blocks -> higher occupancy, cf R6 63% vs R7 35%).
template <bool RELU, bool WRITE_EMB>
__global__ __launch_bounds__(256, 8) void k_spmm(const _Float16* __restrict__ hS,
                                                 const float* __restrict__ als,
                                                 const float* __restrict__ ald,
                                                 const int* __restrict__ cnt,
                                                 const int* __restrict__ roff,
                                                 const u16* __restrict__ csr,
                                                 const float* __restrict__ bias,
                                                 _Float16* __restrict__ gout,
                                                 float* __restrict__ embout) {
  const int cg = blockIdx.x & 7;
  const int tb = (blockIdx.x >> 3) * TPB;
  const int tid = threadIdx.x;
  const int dl = tid >> 2;            // 64 dsts per tile pass
  const int cs = tid & 3;             // head
  const _Float16* __restrict__ hsl = hS + (size_t)cg * NN * 32 + cs * 8;
#pragma unroll 1
  for (int p = 0; p < TPB; ++p) {
    const int n = (tb + p) * 64 + dl;
    float acc[8] = {};
    if (n < NN) {
      const int dd = cnt[n];
      const int ro = roff[n];           // 8-aligned
      const u16x8* crow = (const u16x8*)&csr[ro];
      const float ad = ald[(size_t)n * 4 + cs];
      float den = 0.f;
      const int nch = (dd + 7) >> 3;    // padded chunks of 8
      for (int c = 0; c < nch; ++c) {
        const u16x8 A = crow[c];
        int s[8];
#pragma unroll
        for (int u = 0; u < 8; ++u) s[u] = (int)A[u];
        float av[8];
#pragma unroll
        for (int u = 0; u < 8; ++u) av[u] = als[(size_t)s[u] * 4 + cs];
        f16x8 hv[8];
#pragma unroll
        for (int u = 0; u < 8; ++u) hv[u] = *(const f16x8*)&hsl[(size_t)s[u] * 32];
        const int base = c * 8;
#pragma unroll
        for (int u = 0; u < 8; ++u) {
          float pw = __expf(fminf(lrelu(av[u] + ad), 80.f));
          pw = (base + u < dd) ? pw : 0.f;
          den += pw;
#pragma unroll
          for (int j = 0; j < 8; ++j) acc[j] = fmaf(pw, (float)hv[u][j], acc[j]);
        }
      }
      const float inv = 0.25f / den;  // den > 0: self-loop at slot 0
#pragma unroll
      for (int j = 0; j < 8; ++j) acc[j] *= inv;
    }
    // reduce over heads (lane bits 0,1)
#pragma unroll
    for (int off = 1; off <= 2; off <<= 1)
#pragma unroll
      for (int j = 0; j < 8; ++j) acc[j] += __shfl_xor(acc[j], off, 64);
    if (n < NN && cs == 0) {
      const float4 b0 = *(const float4*)&bias[cg * 8];
      const float4 b1 = *(const float4*)&bias[cg * 8 + 4];
      float o[8];
      o[0] = acc[0] + b0.x; o[1] = acc[1] + b0.y; o[2] = acc[2] + b0.z; o[3] = acc[3] + b0.w;
      o[4] = acc[4] + b1.x; o[5] = acc[5] + b1.y; o[6] = acc[6] + b1.z; o[7] = acc[7] + b1.w;
      if (RELU) {
#pragma unroll
        for (int j = 0; j < 8; ++j) o[j] = fmaxf(o[j], 0.f);
      }
      f16x8 v;
#pragma unroll
      for (int j = 0; j < 8; ++j) v[j] = (_Float16)o[j];
      *(f16x8*)&gout[(size_t)n * 64 + cg * 8] = v;
      if (WRITE_EMB) {
        float4 v0 = {o[0], o[1], o[2], o[3]}, v1 = {o[4], o[5], o[6], o[7]};
        *(float4*)&embout[(size_t)n * 64 + cg * 8] = v0;
        *(float4*)&embout[(size_t)n * 64 + cg * 8 + 4] = v1;
      }
    }
  }
}

// ------- linear (K=64, fp16 in) -> channel-sliced h + als/ald -------
__global__ __launch_bounds__(256) void k_mm64(const _Float16* __restrict__ g,
                                              const _Float16* __restrict__ wt,
                                              const float* __restrict__ a_s,
                                              const float* __restrict__ a_d,
                                              _Float16* __restrict__ hS,
                                              float* __restrict__ als,
                                              float* __restrict__ ald) {
  __shared__ _Float16 stg[4][16 * 68];
  const int lane = threadIdx.x & 63;
  const int wv = threadIdx.x >> 6;
  const int quad = lane >> 4, nn = lane & 15;
  const int row0 = blockIdx.x * 16;
  f16x8 af[2];
#pragma unroll
  for (int kc = 0; kc < 2; ++kc)
    af[kc] = *(const f16x8*)&g[(size_t)(row0 + nn) * 64 + kc * 32 + quad * 8];
  f32x4 accv[4];
  float asf[4], adf[4];
#pragma unroll
  for (int ct = 0; ct < 4; ++ct) {
    const int col = wv * 64 + ct * 16 + nn;
    const f16x8 b0 = *(const f16x8*)&wt[(size_t)col * 64 + quad * 8];
    const f16x8 b1 = *(const f16x8*)&wt[(size_t)col * 64 + 32 + quad * 8];
    asf[ct] = a_s[col];
    adf[ct] = a_d[col];
    f32x4 acc = {0.f, 0.f, 0.f, 0.f};
    acc = __builtin_amdgcn_mfma_f32_16x16x32_f16(af[0], b0, acc, 0, 0, 0);
    acc = __builtin_amdgcn_mfma_f32_16x16x32_f16(af[1], b1, acc, 0, 0, 0);
    accv[ct] = acc;
  }
  store_sliced(hS, stg[wv], accv, row0, wv, quad, nn, lane);
  float sa[4] = {0.f, 0.f, 0.f, 0.f}, sd[4] = {0.f, 0.f, 0.f, 0.f};
#pragma unroll
  for (int ct = 0; ct < 4; ++ct)
#pragma unroll
    for (int r = 0; r < 4; ++r) {
      sa[r] = fmaf(accv[ct][r], asf[ct], sa[r]);
      sd[r] = fmaf(accv[ct][r], adf[ct], sd[r]);
    }
#pragma unroll
  for (int off = 1; off <= 8; off <<= 1)
#pragma unroll
    for (int r = 0; r < 4; ++r) {
      sa[r] += __shfl_xor(sa[r], off, 64);
      sd[r] += __shfl_xor(sd[r], off, 64);
    }
  if (nn == 0) {
#pragma unroll
    for (int r = 0; r < 4; ++r) {
      als[(size_t)(row0 + quad * 4 + r) * 4 + wv] = sa[r];
      ald[(size_t)(row0 + quad * 4 + r) * 4 + wv] = sd[r];
    }
  }
}

// ------- merged post: node-MLP heads (blocks [0,NT)) + pool partials -------
__global__ __launch_bounds__(256) void k_post(const _Float16* __restrict__ g3,
                                              const _Float16* __restrict__ wcat,
                                              const float* __restrict__ aw2,
                                              const float* __restrict__ ab2,
                                              const float* __restrict__ rw2,
                                              const float* __restrict__ rb2,
                                              const float* __restrict__ cw2,
                                              const float* __restrict__ cb2,
                                              float* __restrict__ anomaly,
                                              float* __restrict__ risk,
                                              float* __restrict__ resource,
                                              const float* __restrict__ emb,
                                              const int* __restrict__ batch,
                                              float* __restrict__ part) {
  if (blockIdx.x >= NT) {
    // ---- pooling partials: 8 slices/graph ----
    const int bid = blockIdx.x - NT;
    const int g = bid >> 3, s = bid & 7;
    const int tid = threadIdx.x, c = tid & 63, w = tid >> 6;
    int lo = 0, hi = NN;
    while (lo < hi) { int mid = (lo + hi) >> 1; if (batch[mid] < g) lo = mid + 1; else hi = mid; }
    const int start = lo;
    hi = NN;
    while (lo < hi) { int mid = (lo + hi) >> 1; if (batch[mid] < g + 1) lo = mid + 1; else hi = mid; }
    const int end = lo;
    const int len = end - start;
    const int s0 = start + (int)(((long long)len * s) >> 3);
    const int s1 = start + (int)(((long long)len * (s + 1)) >> 3);
    float sum = 0.f;
    for (int n = s0 + w; n < s1; n += 4) sum += emb[(size_t)n * 64 + c];
    __shared__ float sm[4][64];
    sm[w][c] = sum;
    __syncthreads();
    if (tid < 64)
      part[(size_t)bid * 64 + tid] = sm[0][tid] + sm[1][tid] + sm[2][tid] + sm[3][tid];
    return;
  }
  __shared__ float hb[16][101];
  const int lane = threadIdx.x & 63;
  const int wv = threadIdx.x >> 6;
  const int quad = lane >> 4, nn = lane & 15;
  const int row0 = blockIdx.x * 16;
  const int nct = (wv < 2) ? 2 : 1;
  f16x8 af[2];
#pragma unroll
  for (int kc = 0; kc < 2; ++kc)
    af[kc] = *(const f16x8*)&g3[(size_t)(row0 + nn) * 64 + kc * 32 + quad * 8];
  for (int m = 0; m < nct; ++m) {
    const int ct = (m == 0) ? wv : (4 + wv);
    const int col = ct * 16 + nn;
    const f16x8 b0 = *(const f16x8*)&wcat[(size_t)col * 64 + quad * 8];
    const f16x8 b1 = *(const f16x8*)&wcat[(size_t)col * 64 + 32 + quad * 8];
    f32x4 acc = {0.f, 0.f, 0.f, 0.f};
    acc = __builtin_amdgcn_mfma_f32_16x16x32_f16(af[0], b0, acc, 0, 0, 0);
    acc = __builtin_amdgcn_mfma_f32_16x16x32_f16(af[1], b1, acc, 0, 0, 0);
#pragma unroll
    for (int r = 0; r < 4; ++r)
      hb[quad * 4 + r][col] = fmaxf(acc[r], 0.f);
  }
  __syncthreads();
  if (wv == 0) {
    const int node = lane >> 2, task = lane & 3;
    const float* hrow = hb[node];
    const int n = row0 + node;
    if (task == 0) {
      float s = ab2[0];
#pragma unroll
      for (int k = 0; k < 32; ++k) s = fmaf(hrow[k], aw2[k], s);
      anomaly[n] = 1.f / (1.f + __expf(-s));
    } else if (task == 1) {
      float s = rb2[0];
#pragma unroll
      for (int k = 0; k < 32; ++k) s = fmaf(hrow[32 + k], rw2[k], s);
      risk[n] = 1.f / (1.f + __expf(-s));
    } else if (task == 2) {
      float s0 = cb2[0], s1 = cb2[1], s2 = cb2[2];
#pragma unroll
      for (int k = 0; k < 32; ++k) {
        const float v = hrow[64 + k];
        s0 = fmaf(v, cw2[k * 5 + 0], s0);
        s1 = fmaf(v, cw2[k * 5 + 1], s1);
        s2 = fmaf(v, cw2[k * 5 + 2], s2);
      }
      resource[n * 5 + 0] = s0; resource[n * 5 + 1] = s1; resource[n * 5 + 2] = s2;
    } else {
      float s3 = cb2[3], s4 = cb2[4];
#pragma unroll
      for (int k = 0; k < 32; ++k) {
        const float v = hrow[64 + k];
        s3 = fmaf(v, cw2[k * 5 + 3], s3);
        s4 = fmaf(v, cw2[k * 5 + 4], s4);
      }
      resource[n * 5 + 3] = s3; resource[n * 5 + 4] = s4;
    }
  }
}

// ---------------- pool finish + graph MLP (64 blocks x 64 threads) -------
__global__ void k_pool2(const float* __restrict__ part, const int* __restrict__ batch,
                        const float* __restrict__ gw1, const float* __restrict__ gb1,
                        const float* __restrict__ gw2, const float* __restrict__ gb2,
                        float* __restrict__ logits) {
  const int g = blockIdx.x, tid = threadIdx.x;  // 64 threads = 1 wave
  int lo = 0, hi = NN;
  while (lo < hi) { int mid = (lo + hi) >> 1; if (batch[mid] < g) lo = mid + 1; else hi = mid; }
  const int start = lo;
  hi = NN;
  while (lo < hi) { int mid = (lo + hi) >> 1; if (batch[mid] < g + 1) lo = mid + 1; else hi = mid; }
  const int cntg = lo - start;
  __shared__ float prow[64];
  float v = 0.f;
#pragma unroll
  for (int s = 0; s < 8; ++s) v += part[(size_t)(g * 8 + s) * 64 + tid];
  prow[tid] = v * (1.f / fmaxf((float)cntg, 1.f));
  __syncthreads();
  if (tid < 32) {
    float hG = gb1[tid];
    for (int cc = 0; cc < 64; ++cc) hG = fmaf(prow[cc], gw1[cc * 32 + tid], hG);
    hG = fmaxf(hG, 0.f);
    float p[4];
#pragma unroll
    for (int j = 0; j < 4; ++j) p[j] = hG * gw2[tid * 4 + j];
#pragma unroll
    for (int off = 1; off <= 16; off <<= 1) {
#pragma unroll
      for (int j = 0; j < 4; ++j) p[j] += __shfl_xor(p[j], off, 64);
    }
    if (tid == 0) {
#pragma unroll
      for (int j = 0; j < 4; ++j) logits[g * 4 + j] = p[j] + gb2[j];
    }
  }
}

extern "C" void kernel_launch(void* const* d_in, const int* in_sizes, int n_in,
                              void* d_out, int out_size, void* d_ws, size_t ws_size,
                              hipStream_t stream) {
  const float* x = (const float*)d_in[0];
  const int* ei = (const int*)d_in[1];
  const int* batch = (const int*)d_in[2];
  const float* W1 = (const float*)d_in[3];
  const float* as1 = (const float*)d_in[4];
  const float* ad1 = (const float*)d_in[5];
  const float* b1 = (const float*)d_in[6];
  const float* W2 = (const float*)d_in[7];
  const float* as2 = (const float*)d_in[8];
  const float* ad2 = (const float*)d_in[9];
  const float* b2 = (const float*)d_in[10];
  const float* W3 = (const float*)d_in[11];
  const float* as3 = (const float*)d_in[12];
  const float* ad3 = (const float*)d_in[13];
  const float* b3 = (const float*)d_in[14];
  const float* aw1 = (const float*)d_in[15];
  const float* ab1 = (const float*)d_in[16];
  const float* aw2 = (const float*)d_in[17];
  const float* ab2 = (const float*)d_in[18];
  const float* rw1 = (const float*)d_in[19];
  const float* rb1 = (const float*)d_in[20];
  const float* rw2 = (const float*)d_in[21];
  const float* rb2 = (const float*)d_in[22];
  const float* cw1 = (const float*)d_in[23];
  const float* cb1 = (const float*)d_in[24];
  const float* cw2 = (const float*)d_in[25];
  const float* cb2 = (const float*)d_in[26];
  const float* gw1 = (const float*)d_in[27];
  const float* gb1 = (const float*)d_in[28];
  const float* gw2 = (const float*)d_in[29];
  const float* gb2 = (const float*)d_in[30];

  float* out = (float*)d_out;
  float* emb = out;                       // [N,64]
  float* anomaly = out + NN * 64;         // [N]
  float* risk = anomaly + NN;             // [N]
  float* resource = risk + NN;            // [N,5]
  float* logits = resource + NN * 5;      // [G,4]

  char* ws = (char*)d_ws;
  int* cnt = (int*)ws;            ws += (size_t)NN * 4;
  int* roff = (int*)ws;           ws += (size_t)NN * 4;
  u16* csr = (u16*)ws;            ws += (size_t)NB * CAPP * 2;
  unsigned* ebuf = (unsigned*)ws; ws += (size_t)NB * CAP * 4;
  _Float16* hS = (_Float16*)ws;   ws += (size_t)8 * NN * 32 * 2;
  float* alsA = (float*)ws;       ws += (size_t)NN * 4 * 4;
  float* aldA = (float*)ws;       ws += (size_t)NN * 4 * 4;
  _Float16* g = (_Float16*)ws;    ws += (size_t)NN * 64 * 2;
  _Float16* wt1 = (_Float16*)ws;  ws += (size_t)32768 * 2;
  _Float16* wt2 = (_Float16*)ws;  ws += (size_t)16384 * 2;
  _Float16* wt3 = (_Float16*)ws;  ws += (size_t)16384 * 2;
  _Float16* wcat = (_Float16*)ws; ws += (size_t)6144 * 2;
  int* gcur = (int*)ws;           ws += (size_t)NB * 4;        // memset target
  float* part = (float*)ws;       ws += (size_t)GG * 8 * 64 * 4;

  hipMemsetAsync(gcur, 0, (size_t)NB * 4, stream);
  // tiny weight prep first (dependency of the GEMM half of k_part)
  k_prep<<<280, 256, 0, stream>>>(W1, W2, W3, aw1, rw1, cw1, wt1, wt2, wt3, wcat);
  // pass 1: edge partition into buckets, overlapped with layer-1 linear
  k_part<<<NPB + MMB, 256, 0, stream>>>(ei, gcur, ebuf, x, wt1, as1, ad1,
                                        hS, alsA, aldA);
  // pass 2: per-bucket compact CSR with self-loops, u16 ids, 16B-aligned rows
  k_csr<<<NB, 256, 0, stream>>>(gcur, ebuf, cnt, roff, csr);
  // layer 1: fused softmax + sliced SpMM
  k_spmm<true, false><<<NSB, 256, 0, stream>>>(hS, alsA, aldA, cnt, roff, csr,
                                               b1, g, nullptr);
  // layer 2
  k_mm64<<<NT, 256, 0, stream>>>(g, wt2, as2, ad2, hS, alsA, aldA);
  k_spmm<true, false><<<NSB, 256, 0, stream>>>(hS, alsA, aldA, cnt, roff, csr,
                                               b2, g, nullptr);
  // layer 3 -> emb
  k_mm64<<<NT, 256, 0, stream>>>(g, wt3, as3, ad3, hS, alsA, aldA);
  k_spmm<false, true><<<NSB, 256, 0, stream>>>(hS, alsA, aldA, cnt, roff, csr,
                                               b3, g, emb);
  // merged: node-MLP heads + pooling partials
  k_post<<<NT + GG * 8, 256, 0, stream>>>(g, wcat, aw2, ab2, rw2, rb2, cw2, cb2,
                                          anomaly, risk, resource, emb, batch, part);
  k_pool2<<<GG, 64, 0, stream>>>(part, batch, gw1, gb1, gw2, gb2, logits);
}

// Round 10
// 519.196 us; speedup vs baseline: 2.4782x; 2.4782x over previous
//
#include <hip/hip_runtime.h>
#include <hip/hip_fp16.h>
#include <math.h>

#define NN 50000
#define EE 800000
#define GG 64
#define NT  (NN / 16)            // 3125 16-node tiles (exact)
#define MMB 1024                 // persistent GEMM blocks in merged part+mm kernel

#define EPB 4096                 // edges per partition block
#define NPB ((EE + EPB - 1) / EPB)   // 196 partition blocks
#define NB  ((NN + 255) >> 8)        // 196 dst buckets (256 nodes each)
#define CAP 4608                 // bucket edge capacity: mean 4082 + 8.2 sigma
#define CAPP 6912                // + self slots + 8-align padding (mult of 8)
#define NTA ((NN + 63) / 64)         // 782 agg tiles of 64 dsts
#define TPB 4                    // tiles per spmm block
#define NSB (((NTA + TPB - 1) / TPB) * 8)  // spmm grid

typedef _Float16 f16x8 __attribute__((ext_vector_type(8)));
typedef float f32x4 __attribute__((ext_vector_type(4)));
typedef unsigned short u16;
typedef u16 u16x8 __attribute__((ext_vector_type(8)));

__device__ __forceinline__ float lrelu(float x) { return x > 0.f ? x : 0.2f * x; }

// ---------------- fp16 weight prep (tiny, runs before merged part+mm) ----------
__global__ void k_prep(const float* __restrict__ W1, const float* __restrict__ W2,
                       const float* __restrict__ W3, const float* __restrict__ aw1,
                       const float* __restrict__ rw1, const float* __restrict__ cw1,
                       _Float16* __restrict__ wt1, _Float16* __restrict__ wt2,
                       _Float16* __restrict__ wt3, _Float16* __restrict__ wcat) {
  const int t = blockIdx.x * 256 + threadIdx.x;
  if (t < 32768) {
    const int c = t >> 7, k = t & 127;
    wt1[t] = (_Float16)W1[k * 256 + c];
  } else if (t < 49152) {
    const int u = t - 32768, c = u >> 6, k = u & 63;
    wt2[u] = (_Float16)W2[k * 256 + c];
  } else if (t < 65536) {
    const int u = t - 49152, c = u >> 6, k = u & 63;
    wt3[u] = (_Float16)W3[k * 256 + c];
  } else if (t < 71680) {
    const int u = t - 65536, c = u >> 6, k = u & 63;
    float v = (c < 32) ? aw1[k * 32 + c] : (c < 64) ? rw1[k * 32 + (c - 32)]
                                                    : cw1[k * 32 + (c - 64)];
    wcat[u] = (_Float16)v;
  }
}

// stage wave's fp32 frags -> per-wave LDS fp16 tile (stride 68: conflict-free)
// -> 16B sliced global stores. hS layout: [cg][node][hh*8+j], 64 B/node/slice.
__device__ __forceinline__ void store_sliced(_Float16* __restrict__ hS,
                                             _Float16* __restrict__ lds,  // [16*68]
                                             const f32x4* accv, int row0, int wv,
                                             int quad, int nn, int lane) {
#pragma unroll
  for (int ct = 0; ct < 4; ++ct)
#pragma unroll
    for (int r = 0; r < 4; ++r)
      lds[(quad * 4 + r) * 68 + ct * 16 + nn] = (_Float16)accv[ct][r];
#pragma unroll
  for (int it = 0; it < 2; ++it) {
    const int idx = it * 64 + lane;
    const int row = idx >> 3, cgx = idx & 7;
    const f16x8 v = *(const f16x8*)&lds[row * 68 + cgx * 8];
    *(f16x8*)&hS[((size_t)cgx * NN + row0 + row) * 32 + wv * 8] = v;
  }
}

// ------- pass 1: edge partition into 196 dst-buckets (block-private chunks)
//         merged with layer-1 MFMA GEMM (writes channel-sliced h + als/ald) -------
__global__ __launch_bounds__(256) void k_part(const int* __restrict__ ei,
                                              int* __restrict__ gcur,
                                              unsigned* __restrict__ ebuf,
                                              const float* __restrict__ xin,
                                              const _Float16* __restrict__ wt,
                                              const float* __restrict__ a_s,
                                              const float* __restrict__ a_d,
                                              _Float16* __restrict__ hS,
                                              float* __restrict__ als,
                                              float* __restrict__ ald) {
  if (blockIdx.x < NPB) {
    __shared__ int hist[NB], base[NB], lcur[NB];
    const int tid = threadIdx.x;
    const int e0 = blockIdx.x * EPB;
    const int e1 = min(e0 + EPB, EE);
    for (int i = tid; i < NB; i += 256) hist[i] = 0;
    __syncthreads();
    for (int e = e0 + tid; e < e1; e += 256)
      atomicAdd(&hist[ei[EE + e] >> 8], 1);
    __syncthreads();
    for (int i = tid; i < NB; i += 256) {
      base[i] = (hist[i] > 0) ? atomicAdd(&gcur[i], hist[i]) : 0;
      lcur[i] = 0;
    }
    __syncthreads();
    for (int e = e0 + tid; e < e1; e += 256) {
      const int src = ei[e], dst = ei[EE + e];
      const int b = dst >> 8;
      const int sl = base[b] + atomicAdd(&lcur[b], 1);
      if (sl < CAP)
        ebuf[(size_t)b * CAP + sl] = ((unsigned)(dst & 255) << 16) | (unsigned)src;
    }
    return;
  }
  // ---- layer-1 GEMM: h = x@W1 (fp32 x, in-register cvt), fused al_s/al_d ----
  __shared__ _Float16 stg[4][16 * 68];
  constexpr int K = 128, KC = K / 32;
  const int lane = threadIdx.x & 63;
  const int wv = threadIdx.x >> 6;
  const int quad = lane >> 4, nn = lane & 15;
  f16x8 bf[KC][4];
  float asf[4], adf[4];
#pragma unroll
  for (int ct = 0; ct < 4; ++ct) {
    const int col = wv * 64 + ct * 16 + nn;
#pragma unroll
    for (int kc = 0; kc < KC; ++kc)
      bf[kc][ct] = *(const f16x8*)&wt[(size_t)col * K + kc * 32 + quad * 8];
    asf[ct] = a_s[col];
    adf[ct] = a_d[col];
  }
  for (int rt = blockIdx.x - NPB; rt < NT; rt += MMB) {
    const int row0 = rt * 16;
    const float* xrow = xin + (size_t)(row0 + nn) * K + quad * 8;
    f16x8 af[KC];
#pragma unroll
    for (int kc = 0; kc < KC; ++kc) {
      const float4 u0 = *(const float4*)(xrow + kc * 32);
      const float4 u1 = *(const float4*)(xrow + kc * 32 + 4);
      af[kc][0] = (_Float16)u0.x; af[kc][1] = (_Float16)u0.y;
      af[kc][2] = (_Float16)u0.z; af[kc][3] = (_Float16)u0.w;
      af[kc][4] = (_Float16)u1.x; af[kc][5] = (_Float16)u1.y;
      af[kc][6] = (_Float16)u1.z; af[kc][7] = (_Float16)u1.w;
    }
    f32x4 accv[4];
#pragma unroll
    for (int ct = 0; ct < 4; ++ct) {
      f32x4 acc = {0.f, 0.f, 0.f, 0.f};
#pragma unroll
      for (int kc = 0; kc < KC; ++kc)
        acc = __builtin_amdgcn_mfma_f32_16x16x32_f16(af[kc], bf[kc][ct], acc, 0, 0, 0);
      accv[ct] = acc;
    }
    store_sliced(hS, stg[wv], accv, row0, wv, quad, nn, lane);
    float sa[4] = {0.f, 0.f, 0.f, 0.f}, sd[4] = {0.f, 0.f, 0.f, 0.f};
#pragma unroll
    for (int ct = 0; ct < 4; ++ct)
#pragma unroll
      for (int r = 0; r < 4; ++r) {
        sa[r] = fmaf(accv[ct][r], asf[ct], sa[r]);
        sd[r] = fmaf(accv[ct][r], adf[ct], sd[r]);
      }
#pragma unroll
    for (int off = 1; off <= 8; off <<= 1)
#pragma unroll
      for (int r = 0; r < 4; ++r) {
        sa[r] += __shfl_xor(sa[r], off, 64);
        sd[r] += __shfl_xor(sd[r], off, 64);
      }
    if (nn == 0) {
#pragma unroll
      for (int r = 0; r < 4; ++r) {
        als[(size_t)(row0 + quad * 4 + r) * 4 + wv] = sa[r];
        ald[(size_t)(row0 + quad * 4 + r) * 4 + wv] = sd[r];
      }
    }
  }
}

// ------- pass 2: per-bucket compact CSR (u16 src ids), SELF at slot 0,
//         rows padded to multiples of 8 (16B) — pad slots = own node id -------
__global__ __launch_bounds__(256) void k_csr(const int* __restrict__ gcur,
                                             const unsigned* __restrict__ ebuf,
                                             int* __restrict__ cnt,
                                             int* __restrict__ roff,
                                             u16* __restrict__ csr) {
  __shared__ int c256[256], pre[256], cur[256], wsum[4];
  const int b = blockIdx.x, tid = threadIdx.x;
  c256[tid] = 0;
  __syncthreads();
  const int nE = min(gcur[b], CAP);
  const unsigned* eb = ebuf + (size_t)b * CAP;
  for (int i = tid; i < nE; i += 256) atomicAdd(&c256[eb[i] >> 16], 1);
  __syncthreads();
  const int v = c256[tid] + 1;        // true deg incl self
  const int v8 = (v + 7) & ~7;        // padded row length (16B multiple)
  {
    const int lane = tid & 63, wid = tid >> 6;
    int x = v8;
#pragma unroll
    for (int off = 1; off < 64; off <<= 1) {
      const int y = __shfl_up(x, off, 64);
      if (lane >= off) x += y;
    }
    if (lane == 63) wsum[wid] = x;
    __syncthreads();
    int wo = 0;
    for (int w = 0; w < wid; ++w) wo += wsum[w];
    pre[tid] = wo + x - v8;
    cur[tid] = 1;  // slot 0 = self
  }
  __syncthreads();
  const int node = (b << 8) + tid;
  const int ro = b * CAPP + pre[tid];
  if (node < NN) {
    cnt[node] = v;
    roff[node] = ro;
    csr[ro] = (u16)node;  // self-loop
    for (int i = v; i < v8; ++i) csr[ro + i] = (u16)node;  // padding (p masked)
  }
  for (int i = tid; i < nE; i += 256) {
    const unsigned p = eb[i];
    const int dl = (int)(p >> 16), src = (int)(p & 0xFFFFu);
    const int slot = atomicAdd(&cur[dl], 1);
    csr[b * CAPP + pre[dl] + slot] = (u16)src;
  }
}

// ------- channel-sliced SpMM with fused unnormalized softmax -------
// slice cg = blockIdx%8 -> XCD round-robin (per-XCD hS slice 3.2MB + als 0.8MB
// L2-resident; csr stream u16 = 1.7MB/XCD). One 16B load = 8 edge ids;
// 8 als + 8 hv gathers in flight. ONE lane per (dst, head); den lane-local.
// launch_bounds min-waves = 4 (cap 128 VGPR): R9's (256,8) capped VGPR at 32
// -> 583MB scratch spill, 3.8x slowdown. Keep registers, accept 4-6 waves/SIMD.
template <bool RELU, bool WRITE_EMB>
__global__ __launch_bounds__(256, 4) void k_spmm(const _Float16* __restrict__ hS,
                                                 const float* __restrict__ als,
                                                 const float* __restrict__ ald,
                                                 const int* __restrict__ cnt,
                                                 const int* __restrict__ roff,
                                                 const u16* __restrict__ csr,
                                                 const float* __restrict__ bias,
                                                 _Float16* __restrict__ gout,
                                                 float* __restrict__ embout) {
  const int cg = blockIdx.x & 7;
  const int tb = (blockIdx.x >> 3) * TPB;
  const int tid = threadIdx.x;
  const int dl = tid >> 2;            // 64 dsts per tile pass
  const int cs = tid & 3;             // head
  const _Float16* __restrict__ hsl = hS + (size_t)cg * NN * 32 + cs * 8;
#pragma unroll 1
  for (int p = 0; p < TPB; ++p) {
    const int n = (tb + p) * 64 + dl;
    float acc[8] = {};
    if (n < NN) {
      const int dd = cnt[n];
      const int ro = roff[n];           // 8-aligned
      const u16x8* crow = (const u16x8*)&csr[ro];
      const float ad = ald[(size_t)n * 4 + cs];
      float den = 0.f;
      const int nch = (dd + 7) >> 3;    // padded chunks of 8
      for (int c = 0; c < nch; ++c) {
        const u16x8 A = crow[c];
        int s[8];
#pragma unroll
        for (int u = 0; u < 8; ++u) s[u] = (int)A[u];
        float av[8];
#pragma unroll
        for (int u = 0; u < 8; ++u) av[u] = als[(size_t)s[u] * 4 + cs];
        f16x8 hv[8];
#pragma unroll
        for (int u = 0; u < 8; ++u) hv[u] = *(const f16x8*)&hsl[(size_t)s[u] * 32];
        const int base = c * 8;
#pragma unroll
        for (int u = 0; u < 8; ++u) {
          float pw = __expf(fminf(lrelu(av[u] + ad), 80.f));
          pw = (base + u < dd) ? pw : 0.f;
          den += pw;
#pragma unroll
          for (int j = 0; j < 8; ++j) acc[j] = fmaf(pw, (float)hv[u][j], acc[j]);
        }
      }
      const float inv = 0.25f / den;  // den > 0: self-loop at slot 0
#pragma unroll
      for (int j = 0; j < 8; ++j) acc[j] *= inv;
    }
    // reduce over heads (lane bits 0,1)
#pragma unroll
    for (int off = 1; off <= 2; off <<= 1)
#pragma unroll
      for (int j = 0; j < 8; ++j) acc[j] += __shfl_xor(acc[j], off, 64);
    if (n < NN && cs == 0) {
      const float4 b0 = *(const float4*)&bias[cg * 8];
      const float4 b1 = *(const float4*)&bias[cg * 8 + 4];
      float o[8];
      o[0] = acc[0] + b0.x; o[1] = acc[1] + b0.y; o[2] = acc[2] + b0.z; o[3] = acc[3] + b0.w;
      o[4] = acc[4] + b1.x; o[5] = acc[5] + b1.y; o[6] = acc[6] + b1.z; o[7] = acc[7] + b1.w;
      if (RELU) {
#pragma unroll
        for (int j = 0; j < 8; ++j) o[j] = fmaxf(o[j], 0.f);
      }
      f16x8 v;
#pragma unroll
      for (int j = 0; j < 8; ++j) v[j] = (_Float16)o[j];
      *(f16x8*)&gout[(size_t)n * 64 + cg * 8] = v;
      if (WRITE_EMB) {
        float4 v0 = {o[0], o[1], o[2], o[3]}, v1 = {o[4], o[5], o[6], o[7]};
        *(float4*)&embout[(size_t)n * 64 + cg * 8] = v0;
        *(float4*)&embout[(size_t)n * 64 + cg * 8 + 4] = v1;
      }
    }
  }
}

// ------- linear (K=64, fp16 in) -> channel-sliced h + als/ald -------
__global__ __launch_bounds__(256) void k_mm64(const _Float16* __restrict__ g,
                                              const _Float16* __restrict__ wt,
                                              const float* __restrict__ a_s,
                                              const float* __restrict__ a_d,
                                              _Float16* __restrict__ hS,
                                              float* __restrict__ als,
                                              float* __restrict__ ald) {
  __shared__ _Float16 stg[4][16 * 68];
  const int lane = threadIdx.x & 63;
  const int wv = threadIdx.x >> 6;
  const int quad = lane >> 4, nn = lane & 15;
  const int row0 = blockIdx.x * 16;
  f16x8 af[2];
#pragma unroll
  for (int kc = 0; kc < 2; ++kc)
    af[kc] = *(const f16x8*)&g[(size_t)(row0 + nn) * 64 + kc * 32 + quad * 8];
  f32x4 accv[4];
  float asf[4], adf[4];
#pragma unroll
  for (int ct = 0; ct < 4; ++ct) {
    const int col = wv * 64 + ct * 16 + nn;
    const f16x8 b0 = *(const f16x8*)&wt[(size_t)col * 64 + quad * 8];
    const f16x8 b1 = *(const f16x8*)&wt[(size_t)col * 64 + 32 + quad * 8];
    asf[ct] = a_s[col];
    adf[ct] = a_d[col];
    f32x4 acc = {0.f, 0.f, 0.f, 0.f};
    acc = __builtin_amdgcn_mfma_f32_16x16x32_f16(af[0], b0, acc, 0, 0, 0);
    acc = __builtin_amdgcn_mfma_f32_16x16x32_f16(af[1], b1, acc, 0, 0, 0);
    accv[ct] = acc;
  }
  store_sliced(hS, stg[wv], accv, row0, wv, quad, nn, lane);
  float sa[4] = {0.f, 0.f, 0.f, 0.f}, sd[4] = {0.f, 0.f, 0.f, 0.f};
#pragma unroll
  for (int ct = 0; ct < 4; ++ct)
#pragma unroll
    for (int r = 0; r < 4; ++r) {
      sa[r] = fmaf(accv[ct][r], asf[ct], sa[r]);
      sd[r] = fmaf(accv[ct][r], adf[ct], sd[r]);
    }
#pragma unroll
  for (int off = 1; off <= 8; off <<= 1)
#pragma unroll
    for (int r = 0; r < 4; ++r) {
      sa[r] += __shfl_xor(sa[r], off, 64);
      sd[r] += __shfl_xor(sd[r], off, 64);
    }
  if (nn == 0) {
#pragma unroll
    for (int r = 0; r < 4; ++r) {
      als[(size_t)(row0 + quad * 4 + r) * 4 + wv] = sa[r];
      ald[(size_t)(row0 + quad * 4 + r) * 4 + wv] = sd[r];
    }
  }
}

// ------- merged post: node-MLP heads (blocks [0,NT)) + pool partials -------
__global__ __launch_bounds__(256) void k_post(const _Float16* __restrict__ g3,
                                              const _Float16* __restrict__ wcat,
                                              const float* __restrict__ aw2,
                                              const float* __restrict__ ab2,
                                              const float* __restrict__ rw2,
                                              const float* __restrict__ rb2,
                                              const float* __restrict__ cw2,
                                              const float* __restrict__ cb2,
                                              float* __restrict__ anomaly,
                                              float* __restrict__ risk,
                                              float* __restrict__ resource,
                                              const float* __restrict__ emb,
                                              const int* __restrict__ batch,
                                              float* __restrict__ part) {
  if (blockIdx.x >= NT) {
    // ---- pooling partials: 8 slices/graph ----
    const int bid = blockIdx.x - NT;
    const int g = bid >> 3, s = bid & 7;
    const int tid = threadIdx.x, c = tid & 63, w = tid >> 6;
    int lo = 0, hi = NN;
    while (lo < hi) { int mid = (lo + hi) >> 1; if (batch[mid] < g) lo = mid + 1; else hi = mid; }
    const int start = lo;
    hi = NN;
    while (lo < hi) { int mid = (lo + hi) >> 1; if (batch[mid] < g + 1) lo = mid + 1; else hi = mid; }
    const int end = lo;
    const int len = end - start;
    const int s0 = start + (int)(((long long)len * s) >> 3);
    const int s1 = start + (int)(((long long)len * (s + 1)) >> 3);
    float sum = 0.f;
    for (int n = s0 + w; n < s1; n += 4) sum += emb[(size_t)n * 64 + c];
    __shared__ float sm[4][64];
    sm[w][c] = sum;
    __syncthreads();
    if (tid < 64)
      part[(size_t)bid * 64 + tid] = sm[0][tid] + sm[1][tid] + sm[2][tid] + sm[3][tid];
    return;
  }
  __shared__ float hb[16][101];
  const int lane = threadIdx.x & 63;
  const int wv = threadIdx.x >> 6;
  const int quad = lane >> 4, nn = lane & 15;
  const int row0 = blockIdx.x * 16;
  const int nct = (wv < 2) ? 2 : 1;
  f16x8 af[2];
#pragma unroll
  for (int kc = 0; kc < 2; ++kc)
    af[kc] = *(const f16x8*)&g3[(size_t)(row0 + nn) * 64 + kc * 32 + quad * 8];
  for (int m = 0; m < nct; ++m) {
    const int ct = (m == 0) ? wv : (4 + wv);
    const int col = ct * 16 + nn;
    const f16x8 b0 = *(const f16x8*)&wcat[(size_t)col * 64 + quad * 8];
    const f16x8 b1 = *(const f16x8*)&wcat[(size_t)col * 64 + 32 + quad * 8];
    f32x4 acc = {0.f, 0.f, 0.f, 0.f};
    acc = __builtin_amdgcn_mfma_f32_16x16x32_f16(af[0], b0, acc, 0, 0, 0);
    acc = __builtin_amdgcn_mfma_f32_16x16x32_f16(af[1], b1, acc, 0, 0, 0);
#pragma unroll
    for (int r = 0; r < 4; ++r)
      hb[quad * 4 + r][col] = fmaxf(acc[r], 0.f);
  }
  __syncthreads();
  if (wv == 0) {
    const int node = lane >> 2, task = lane & 3;
    const float* hrow = hb[node];
    const int n = row0 + node;
    if (task == 0) {
      float s = ab2[0];
#pragma unroll
      for (int k = 0; k < 32; ++k) s = fmaf(hrow[k], aw2[k], s);
      anomaly[n] = 1.f / (1.f + __expf(-s));
    } else if (task == 1) {
      float s = rb2[0];
#pragma unroll
      for (int k = 0; k < 32; ++k) s = fmaf(hrow[32 + k], rw2[k], s);
      risk[n] = 1.f / (1.f + __expf(-s));
    } else if (task == 2) {
      float s0 = cb2[0], s1 = cb2[1], s2 = cb2[2];
#pragma unroll
      for (int k = 0; k < 32; ++k) {
        const float v = hrow[64 + k];
        s0 = fmaf(v, cw2[k * 5 + 0], s0);
        s1 = fmaf(v, cw2[k * 5 + 1], s1);
        s2 = fmaf(v, cw2[k * 5 + 2], s2);
      }
      resource[n * 5 + 0] = s0; resource[n * 5 + 1] = s1; resource[n * 5 + 2] = s2;
    } else {
      float s3 = cb2[3], s4 = cb2[4];
#pragma unroll
      for (int k = 0; k < 32; ++k) {
        const float v = hrow[64 + k];
        s3 = fmaf(v, cw2[k * 5 + 3], s3);
        s4 = fmaf(v, cw2[k * 5 + 4], s4);
      }
      resource[n * 5 + 3] = s3; resource[n * 5 + 4] = s4;
    }
  }
}

// ---------------- pool finish + graph MLP (64 blocks x 64 threads) -------
__global__ void k_pool2(const float* __restrict__ part, const int* __restrict__ batch,
                        const float* __restrict__ gw1, const float* __restrict__ gb1,
                        const float* __restrict__ gw2, const float* __restrict__ gb2,
                        float* __restrict__ logits) {
  const int g = blockIdx.x, tid = threadIdx.x;  // 64 threads = 1 wave
  int lo = 0, hi = NN;
  while (lo < hi) { int mid = (lo + hi) >> 1; if (batch[mid] < g) lo = mid + 1; else hi = mid; }
  const int start = lo;
  hi = NN;
  while (lo < hi) { int mid = (lo + hi) >> 1; if (batch[mid] < g + 1) lo = mid + 1; else hi = mid; }
  const int cntg = lo - start;
  __shared__ float prow[64];
  float v = 0.f;
#pragma unroll
  for (int s = 0; s < 8; ++s) v += part[(size_t)(g * 8 + s) * 64 + tid];
  prow[tid] = v * (1.f / fmaxf((float)cntg, 1.f));
  __syncthreads();
  if (tid < 32) {
    float hG = gb1[tid];
    for (int cc = 0; cc < 64; ++cc) hG = fmaf(prow[cc], gw1[cc * 32 + tid], hG);
    hG = fmaxf(hG, 0.f);
    float p[4];
#pragma unroll
    for (int j = 0; j < 4; ++j) p[j] = hG * gw2[tid * 4 + j];
#pragma unroll
    for (int off = 1; off <= 16; off <<= 1) {
#pragma unroll
      for (int j = 0; j < 4; ++j) p[j] += __shfl_xor(p[j], off, 64);
    }
    if (tid == 0) {
#pragma unroll
      for (int j = 0; j < 4; ++j) logits[g * 4 + j] = p[j] + gb2[j];
    }
  }
}

extern "C" void kernel_launch(void* const* d_in, const int* in_sizes, int n_in,
                              void* d_out, int out_size, void* d_ws, size_t ws_size,
                              hipStream_t stream) {
  const float* x = (const float*)d_in[0];
  const int* ei = (const int*)d_in[1];
  const int* batch = (const int*)d_in[2];
  const float* W1 = (const float*)d_in[3];
  const float* as1 = (const float*)d_in[4];
  const float* ad1 = (const float*)d_in[5];
  const float* b1 = (const float*)d_in[6];
  const float* W2 = (const float*)d_in[7];
  const float* as2 = (const float*)d_in[8];
  const float* ad2 = (const float*)d_in[9];
  const float* b2 = (const float*)d_in[10];
  const float* W3 = (const float*)d_in[11];
  const float* as3 = (const float*)d_in[12];
  const float* ad3 = (const float*)d_in[13];
  const float* b3 = (const float*)d_in[14];
  const float* aw1 = (const float*)d_in[15];
  const float* ab1 = (const float*)d_in[16];
  const float* aw2 = (const float*)d_in[17];
  const float* ab2 = (const float*)d_in[18];
  const float* rw1 = (const float*)d_in[19];
  const float* rb1 = (const float*)d_in[20];
  const float* rw2 = (const float*)d_in[21];
  const float* rb2 = (const float*)d_in[22];
  const float* cw1 = (const float*)d_in[23];
  const float* cb1 = (const float*)d_in[24];
  const float* cw2 = (const float*)d_in[25];
  const float* cb2 = (const float*)d_in[26];
  const float* gw1 = (const float*)d_in[27];
  const float* gb1 = (const float*)d_in[28];
  const float* gw2 = (const float*)d_in[29];
  const float* gb2 = (const float*)d_in[30];

  float* out = (float*)d_out;
  float* emb = out;                       // [N,64]
  float* anomaly = out + NN * 64;         // [N]
  float* risk = anomaly + NN;             // [N]
  float* resource = risk + NN;            // [N,5]
  float* logits = resource + NN * 5;      // [G,4]

  char* ws = (char*)d_ws;
  int* cnt = (int*)ws;            ws += (size_t)NN * 4;
  int* roff = (int*)ws;           ws += (size_t)NN * 4;
  u16* csr = (u16*)ws;            ws += (size_t)NB * CAPP * 2;
  unsigned* ebuf = (unsigned*)ws; ws += (size_t)NB * CAP * 4;
  _Float16* hS = (_Float16*)ws;   ws += (size_t)8 * NN * 32 * 2;
  float* alsA = (float*)ws;       ws += (size_t)NN * 4 * 4;
  float* aldA = (float*)ws;       ws += (size_t)NN * 4 * 4;
  _Float16* g = (_Float16*)ws;    ws += (size_t)NN * 64 * 2;
  _Float16* wt1 = (_Float16*)ws;  ws += (size_t)32768 * 2;
  _Float16* wt2 = (_Float16*)ws;  ws += (size_t)16384 * 2;
  _Float16* wt3 = (_Float16*)ws;  ws += (size_t)16384 * 2;
  _Float16* wcat = (_Float16*)ws; ws += (size_t)6144 * 2;
  int* gcur = (int*)ws;           ws += (size_t)NB * 4;        // memset target
  float* part = (float*)ws;       ws += (size_t)GG * 8 * 64 * 4;

  hipMemsetAsync(gcur, 0, (size_t)NB * 4, stream);
  // tiny weight prep first (dependency of the GEMM half of k_part)
  k_prep<<<280, 256, 0, stream>>>(W1, W2, W3, aw1, rw1, cw1, wt1, wt2, wt3, wcat);
  // pass 1: edge partition into buckets, overlapped with layer-1 linear
  k_part<<<NPB + MMB, 256, 0, stream>>>(ei, gcur, ebuf, x, wt1, as1, ad1,
                                        hS, alsA, aldA);
  // pass 2: per-bucket compact CSR with self-loops, u16 ids, 16B-aligned rows
  k_csr<<<NB, 256, 0, stream>>>(gcur, ebuf, cnt, roff, csr);
  // layer 1: fused softmax + sliced SpMM
  k_spmm<true, false><<<NSB, 256, 0, stream>>>(hS, alsA, aldA, cnt, roff, csr,
                                               b1, g, nullptr);
  // layer 2
  k_mm64<<<NT, 256, 0, stream>>>(g, wt2, as2, ad2, hS, alsA, aldA);
  k_spmm<true, false><<<NSB, 256, 0, stream>>>(hS, alsA, aldA, cnt, roff, csr,
                                               b2, g, nullptr);
  // layer 3 -> emb
  k_mm64<<<NT, 256, 0, stream>>>(g, wt3, as3, ad3, hS, alsA, aldA);
  k_spmm<false, true><<<NSB, 256, 0, stream>>>(hS, alsA, aldA, cnt, roff, csr,
                                               b3, g, emb);
  // merged: node-MLP heads + pooling partials
  k_post<<<NT + GG * 8, 256, 0, stream>>>(g, wcat, aw2, ab2, rw2, rb2, cw2, cb2,
                                          anomaly, risk, resource, emb, batch, part);
  k_pool2<<<GG, 64, 0, stream>>>(part, batch, gw1, gb1, gw2, gb2, logits);
}